// Round 6
// baseline (297.537 us; speedup 1.0000x reference)
//
#include <hip/hip_runtime.h>

// AI4Urban fused CFD timestep on 128^3 f32 grid.
// Round 6: momentum split into per-component kernels (5 weight-sets, ~20 acc
// regs) to restore occupancy; residual kernels restreamed per z-plane to cut
// VGPR. Plane-major grid kept (r5's locality win).

#define NN 128
#define NF (NN*NN*NN)   // 2097152

// ---------- row prep ----------

__device__ __forceinline__ void prep9(int z, int y, int rb[9], bool rn[9]) {
  int zi[3] = {z > 0 ? z-1 : 0, z, z < NN-1 ? z+1 : NN-1};
  int yi[3] = {y > 0 ? y-1 : 0, y, y < NN-1 ? y+1 : NN-1};
  bool zo[3] = {z == 0, false, z == NN-1};
  bool yo[3] = {y == 0, false, y == NN-1};
#pragma unroll
  for (int a = 0; a < 3; ++a)
#pragma unroll
    for (int b = 0; b < 3; ++b) {
      rb[a*3+b] = (zi[a]*NN + yi[b])*NN;
      rn[a*3+b] = zo[a] | yo[b];
    }
}

// 4-set stencil over one field (x-quad), center returned.
template<bool NEG>
__device__ __forceinline__ void sten4(
    const float* __restrict__ f, const int rb[9], const bool rn[9],
    bool lo, bool hi, int x0,
    const float* __restrict__ w0p, const float* __restrict__ w1p,
    const float* __restrict__ w2p, const float* __restrict__ w3p,
    float acc[4][4], float4* center) {
  const float* const Ws[4] = {w0p, w1p, w2p, w3p};
#pragma unroll
  for (int r = 0; r < 9; ++r) {
    int base = rb[r] + x0;
    float4 c = *(const float4*)(f + base);
    float m1 = f[base - (lo ? 0 : 1)];
    float p4 = f[base + (hi ? 3 : 4)];
    if (NEG) {
      float sr = rn[r] ? -1.f : 1.f;
      m1 *= (rn[r] | lo) ? -1.f : 1.f;
      p4 *= (rn[r] | hi) ? -1.f : 1.f;
      c.x *= sr; c.y *= sr; c.z *= sr; c.w *= sr;
    }
    if (r == 4 && center) *center = c;
    float t[6] = {m1, c.x, c.y, c.z, c.w, p4};
#pragma unroll
    for (int s = 0; s < 4; ++s) {
      const float* W = Ws[s];
      float a0 = W[r*3+0], a1 = W[r*3+1], a2 = W[r*3+2];
#pragma unroll
      for (int k = 0; k < 4; ++k)
        acc[s][k] = fmaf(a0, t[k], fmaf(a1, t[k+1], fmaf(a2, t[k+2], acc[s][k])));
    }
  }
}

// 1-set stencil (pressure gradient for one component).
__device__ __forceinline__ void sten1(
    const float* __restrict__ f, const int rb[9],
    bool lo, bool hi, int x0, const float* __restrict__ W, float acc[4]) {
#pragma unroll
  for (int r = 0; r < 9; ++r) {
    int base = rb[r] + x0;
    float4 c = *(const float4*)(f + base);
    float m1 = f[base - (lo ? 0 : 1)];
    float p4 = f[base + (hi ? 3 : 4)];
    float t[6] = {m1, c.x, c.y, c.z, c.w, p4};
    float a0 = W[r*3+0], a1 = W[r*3+1], a2 = W[r*3+2];
#pragma unroll
    for (int k = 0; k < 4; ++k)
      acc[k] = fmaf(a0, t[k], fmaf(a1, t[k+1], fmaf(a2, t[k+2], acc[k])));
  }
}

// 3-set stencil (projection).
__device__ __forceinline__ void sten_p3(
    const float* __restrict__ f, const int rb[9],
    bool lo, bool hi, int x0,
    const float* __restrict__ w0p, const float* __restrict__ w1p,
    const float* __restrict__ w2p, float acc[3][4]) {
  const float* const Ws[3] = {w0p, w1p, w2p};
#pragma unroll
  for (int r = 0; r < 9; ++r) {
    int base = rb[r] + x0;
    float4 c = *(const float4*)(f + base);
    float m1 = f[base - (lo ? 0 : 1)];
    float p4 = f[base + (hi ? 3 : 4)];
    float t[6] = {m1, c.x, c.y, c.z, c.w, p4};
#pragma unroll
    for (int s = 0; s < 3; ++s) {
      const float* W = Ws[s];
      float a0 = W[r*3+0], a1 = W[r*3+1], a2 = W[r*3+2];
#pragma unroll
      for (int k = 0; k < 4; ++k)
        acc[s][k] = fmaf(a0, t[k], fmaf(a1, t[k+1], fmaf(a2, t[k+2], acc[s][k])));
    }
  }
}

// ---------- kernels ----------

__global__ void __launch_bounds__(256) k_solid3(
    float* __restrict__ du, float* __restrict__ dv, float* __restrict__ dw,
    const float* __restrict__ su, const float* __restrict__ sv, const float* __restrict__ sw,
    const float* __restrict__ sg, const float* __restrict__ dtp) {
  int i = blockIdx.x*256 + threadIdx.x;
  if (i >= NF/4) return;
  float dt = dtp[0];
  float4 s4 = ((const float4*)sg)[i];
  float4 a4 = ((const float4*)su)[i];
  float4 b4 = ((const float4*)sv)[i];
  float4 c4 = ((const float4*)sw)[i];
  float4 d4 = make_float4(1.f + dt*s4.x, 1.f + dt*s4.y, 1.f + dt*s4.z, 1.f + dt*s4.w);
  ((float4*)du)[i] = make_float4(a4.x/d4.x, a4.y/d4.y, a4.z/d4.z, a4.w/d4.w);
  ((float4*)dv)[i] = make_float4(b4.x/d4.x, b4.y/d4.y, b4.z/d4.z, b4.w/d4.w);
  ((float4*)dw)[i] = make_float4(c4.x/d4.x, c4.y/d4.y, c4.z/d4.z, c4.w/d4.w);
}

// One momentum component.
//   CI: which advecting slot equals the stencil-center (0=u,1=v,2=w).
//   NEG = (CI==0): u-field halo factor -1.
//   QALIAS: qbase == stencil center (predictor).
//   a1p/a2p: the two advecting fields that are NOT the center (in u,v,w order).
template<int CI, bool QALIAS>
__global__ void __launch_bounds__(256) k_momc(
    float* __restrict__ dst,
    const float* __restrict__ sq, const float* __restrict__ pf,
    const float* __restrict__ a1p, const float* __restrict__ a2p,
    const float* __restrict__ qb, const float* __restrict__ sg,
    const float* __restrict__ wx, const float* __restrict__ wy,
    const float* __restrict__ wz, const float* __restrict__ wd,
    const float* __restrict__ wp,
    const float* __restrict__ dtp, float scale) {
  int x0 = threadIdx.x * 4;
  int y  = blockIdx.x * 8 + threadIdx.y;   // yband fastest
  int z  = blockIdx.y;                      // z slowest
  bool lo = (x0 == 0), hi = (x0 == NN-4);
  int rb[9]; bool rn[9];
  prep9(z, y, rb, rn);
  float dt = dtp[0];
  int i4 = ((z*NN + y)*NN + x0) >> 2;

  // issue pointwise loads early
  float4 a1_4 = ((const float4*)a1p)[i4];
  float4 a2_4 = ((const float4*)a2p)[i4];
  float4 sg4  = ((const float4*)sg)[i4];
  float4 qb4;
  if (!QALIAS) qb4 = ((const float4*)qb)[i4];

  float acc[4][4] = {};   // {wx,wy,wz,wd} over sq
  float accP[4]   = {};   // wp over pf
  float4 cen;
  sten4<(CI==0)>(sq, rb, rn, lo, hi, x0, wx, wy, wz, wd, acc, &cen);
  sten1(pf, rb, lo, hi, x0, wp, accP);

  float sw27 = 0.f;
#pragma unroll
  for (int j = 0; j < 27; ++j) sw27 += wd[j];

  float cenv[4] = {cen.x, cen.y, cen.z, cen.w};
  float a1v[4] = {a1_4.x, a1_4.y, a1_4.z, a1_4.w};
  float a2v[4] = {a2_4.x, a2_4.y, a2_4.z, a2_4.w};
  float sgv[4] = {sg4.x, sg4.y, sg4.z, sg4.w};
  float o[4];
#pragma unroll
  for (int k = 0; k < 4; ++k) {
    float cu, cv, cw;
    if (CI == 0) { cu = cenv[k]; cv = a1v[k]; cw = a2v[k]; }
    else if (CI == 1) { cu = a1v[k]; cv = cenv[k]; cw = a2v[k]; }
    else { cu = a1v[k]; cv = a2v[k]; cw = cenv[k]; }
    float kk = acc[3][k] - 0.5f*sw27*cenv[k];
    float q = QALIAS ? cenv[k]
            : (k==0 ? qb4.x : k==1 ? qb4.y : k==2 ? qb4.z : qb4.w);
    float r = q + scale*dt*(0.001f*kk - cu*acc[0][k] - cv*acc[1][k] - cw*acc[2][k])
            - accP[k]*dt;
    o[k] = r / (1.0f + dt*sgv[k]);
  }
  ((float4*)dst)[i4] = make_float4(o[0], o[1], o[2], o[3]);
}

// ---------- coarse-cell kernels (2x2x2 fine ownership, plane-streamed) ----------

__device__ __forceinline__ void row4(const float* __restrict__ f, int base,
                                     bool lo, bool hi, float t[4]) {
  float2 c = *(const float2*)(f + base);
  t[0] = f[base - (lo ? 0 : 1)];
  t[1] = c.x; t[2] = c.y;
  t[3] = f[base + (hi ? 1 : 2)];
}

__device__ __forceinline__ void prep16(int Z, int Y, int rb[16], bool rn[16]) {
  int z0 = 2*Z, y0 = 2*Y;
  int zi[4] = {z0 > 0 ? z0-1 : 0, z0, z0+1, z0+2 < NN ? z0+2 : NN-1};
  int yi[4] = {y0 > 0 ? y0-1 : 0, y0, y0+1, y0+2 < NN ? y0+2 : NN-1};
  bool zo[4] = {Z == 0, false, false, Z == 63};
  bool yo[4] = {Y == 0, false, false, Y == 63};
#pragma unroll
  for (int a = 0; a < 4; ++a)
#pragma unroll
    for (int b = 0; b < 4; ++b) {
      rb[a*4+b] = (zi[a]*NN + yi[b])*NN;
      rn[a*4+b] = zo[a] | yo[b];
    }
}

// Plane-streamed 27-tap conv over the 4x4x4 window: only 16 tap floats live.
template<bool NEG>
__device__ __forceinline__ void cc_acc(
    const float* __restrict__ f, const float* __restrict__ W,
    const int rb[16], const bool rn[16], bool lo, bool hi, int x0,
    float out8[8]) {
#pragma unroll
  for (int zp = 0; zp < 4; ++zp) {
    float t[4][4];
#pragma unroll
    for (int yp = 0; yp < 4; ++yp) {
      row4(f, rb[zp*4+yp] + x0, lo, hi, t[yp]);
      if (NEG) {
        bool rno = rn[zp*4+yp];
        float sr = rno ? -1.f : 1.f;
        t[yp][1] *= sr; t[yp][2] *= sr;
        t[yp][0] *= (rno | lo) ? -1.f : 1.f;
        t[yp][3] *= (rno | hi) ? -1.f : 1.f;
      }
    }
#pragma unroll
    for (int dz = 0; dz < 2; ++dz) {
      int a = zp - dz;
      if (a < 0 || a > 2) continue;
#pragma unroll
      for (int oy = 0; oy < 2; ++oy)
#pragma unroll
        for (int b = 0; b < 3; ++b) {
          const float* tr = t[oy + b];
          float w0 = W[(a*3+b)*3+0], w1 = W[(a*3+b)*3+1], w2 = W[(a*3+b)*3+2];
#pragma unroll
          for (int dx = 0; dx < 2; ++dx)
            out8[(dz*2+oy)*2+dx] =
              fmaf(w0, tr[dx], fmaf(w1, tr[dx+1], fmaf(w2, tr[dx+2], out8[(dz*2+oy)*2+dx])));
        }
    }
  }
}

// it0: b = -(div)/dt, rfine = A(p0)-b, rc1 = restrict(rfine).
__global__ void __launch_bounds__(256) k_bdiv_resres(
    float* __restrict__ bb, float* __restrict__ rfine, float* __restrict__ rc1,
    const float* __restrict__ su, const float* __restrict__ sv, const float* __restrict__ sw,
    const float* __restrict__ pf,
    const float* __restrict__ wx, const float* __restrict__ wy, const float* __restrict__ wz,
    const float* __restrict__ wA, const float* __restrict__ wr,
    const float* __restrict__ dtp) {
  int i = blockIdx.x*256 + threadIdx.x;
  if (i >= 64*64*64) return;
  int X = i & 63, Y = (i >> 6) & 63, Z = i >> 12;
  bool lo = (X == 0), hi = (X == 63);
  int x0 = 2*X;
  int rb[16]; bool rn[16];
  prep16(Z, Y, rb, rn);
  float rdt = 1.0f / dtp[0];

  float s8[8] = {};
  cc_acc<true >(su, wx, rb, rn, lo, hi, x0, s8);
  cc_acc<false>(sv, wy, rb, rn, lo, hi, x0, s8);
  cc_acc<false>(sw, wz, rb, rn, lo, hi, x0, s8);
  float a8[8] = {};
  cc_acc<false>(pf, wA, rb, rn, lo, hi, x0, a8);

  float rsum = 0.f;
#pragma unroll
  for (int f = 0; f < 8; ++f) {
    int dz = f >> 2, dy = (f >> 1) & 1, dx = f & 1;
    float bcell = -s8[f] * rdt;
    float rcell = a8[f] - bcell;
    int idx = ((2*Z+dz)*NN + (2*Y+dy))*NN + x0 + dx;
    bb[idx] = bcell;
    rfine[idx] = rcell;
    rsum = fmaf(wr[(dz*2+dy)*2+dx], rcell, rsum);
  }
  rc1[i] = rsum;
}

// it>=1 residual: rfine = A(pst) - b, rc1 = restrict(rfine).
__global__ void __launch_bounds__(256) k_resres1(
    float* __restrict__ rfine, float* __restrict__ rc1,
    const float* __restrict__ pf, const float* __restrict__ bb,
    const float* __restrict__ wA, const float* __restrict__ wr) {
  int i = blockIdx.x*256 + threadIdx.x;
  if (i >= 64*64*64) return;
  int X = i & 63, Y = (i >> 6) & 63, Z = i >> 12;
  bool lo = (X == 0), hi = (X == 63);
  int x0 = 2*X;
  int rb[16]; bool rn[16];
  prep16(Z, Y, rb, rn);
  float a8[8] = {};
  cc_acc<false>(pf, wA, rb, rn, lo, hi, x0, a8);
  float rsum = 0.f;
#pragma unroll
  for (int f = 0; f < 8; ++f) {
    int dz = f >> 2, dy = (f >> 1) & 1, dx = f & 1;
    int idx = ((2*Z+dz)*NN + (2*Y+dy))*NN + x0 + dx;
    float rcell = a8[f] - bb[idx];
    rfine[idx] = rcell;
    rsum = fmaf(wr[(dz*2+dy)*2+dx], rcell, rsum);
  }
  rc1[i] = rsum;
}

__global__ void __launch_bounds__(256) k_restrict(
    float* __restrict__ dst, const float* __restrict__ src,
    const float* __restrict__ wr, int no) {
  int i = blockIdx.x*256 + threadIdx.x;
  int n3 = no*no*no;
  if (i >= n3) return;
  int x = i % no; int t = i / no; int y = t % no; int z = t / no;
  int ni = 2*no;
  float s = 0.f;
#pragma unroll
  for (int a = 0; a < 2; ++a)
#pragma unroll
    for (int b = 0; b < 2; ++b)
#pragma unroll
      for (int c = 0; c < 2; ++c)
        s = fmaf(wr[(a*2+b)*2+c], src[((2*z+a)*ni + (2*y+b))*ni + (2*x+c)], s);
  dst[i] = s;
}

__device__ __forceinline__ float azb_prol(const float* __restrict__ wh, int hs, int s,
    int z, int y, int x, const float* __restrict__ wA) {
  float acc = 0.f;
#pragma unroll
  for (int a = 0; a < 3; ++a) { int zz = z + a - 1; if ((unsigned)zz >= (unsigned)s) continue;
#pragma unroll
    for (int b = 0; b < 3; ++b) { int yy = y + b - 1; if ((unsigned)yy >= (unsigned)s) continue;
#pragma unroll
      for (int c = 0; c < 3; ++c) { int xx = x + c - 1; if ((unsigned)xx >= (unsigned)s) continue;
        acc = fmaf(wA[(a*3+b)*3+c], wh[((zz>>1)*hs + (yy>>1))*hs + (xx>>1)], acc);
      } } }
  return acc;
}

__global__ void __launch_bounds__(512) k_mg_small(
    float* __restrict__ w16, float* __restrict__ r_o,
    const float* __restrict__ rc2,
    const float* __restrict__ wA, const float* __restrict__ wr) {
  __shared__ float r16[4096];
  __shared__ float r8[512];
  __shared__ float r4[64];
  __shared__ float r2[8];
  __shared__ float wa[512];
  __shared__ float wb[64];
  __shared__ float scal[2];
  int tid = threadIdx.x;
  float diag = wA[13];
  float wrl[8];
#pragma unroll
  for (int j = 0; j < 8; ++j) wrl[j] = wr[j];

  for (int j = tid; j < 4096; j += 512) {
    int x = j & 15, y = (j >> 4) & 15, z = j >> 8;
    float s = 0.f;
#pragma unroll
    for (int a = 0; a < 2; ++a)
#pragma unroll
      for (int b = 0; b < 2; ++b)
#pragma unroll
        for (int c = 0; c < 2; ++c)
          s = fmaf(wrl[(a*2+b)*2+c], rc2[((2*z+a)*32 + (2*y+b))*32 + (2*x+c)], s);
    r16[j] = s;
  }
  __syncthreads();
  {
    int j = tid;
    int x = j & 7, y = (j >> 3) & 7, z = j >> 6;
    float s = 0.f;
#pragma unroll
    for (int a = 0; a < 2; ++a)
#pragma unroll
      for (int b = 0; b < 2; ++b)
#pragma unroll
        for (int c = 0; c < 2; ++c)
          s = fmaf(wrl[(a*2+b)*2+c], r16[((2*z+a)*16 + (2*y+b))*16 + (2*x+c)], s);
    r8[j] = s;
  }
  __syncthreads();
  if (tid < 64) {
    int x = tid & 3, y = (tid >> 2) & 3, z = tid >> 4;
    float s = 0.f;
#pragma unroll
    for (int a = 0; a < 2; ++a)
#pragma unroll
      for (int b = 0; b < 2; ++b)
#pragma unroll
        for (int c = 0; c < 2; ++c)
          s = fmaf(wrl[(a*2+b)*2+c], r8[((2*z+a)*8 + (2*y+b))*8 + (2*x+c)], s);
    r4[tid] = s;
  }
  __syncthreads();
  if (tid < 8) {
    int x = tid & 1, y = (tid >> 1) & 1, z = tid >> 2;
    float s = 0.f;
#pragma unroll
    for (int a = 0; a < 2; ++a)
#pragma unroll
      for (int b = 0; b < 2; ++b)
#pragma unroll
        for (int c = 0; c < 2; ++c)
          s = fmaf(wrl[(a*2+b)*2+c], r4[((2*z+a)*4 + (2*y+b))*4 + (2*x+c)], s);
    r2[tid] = s;
  }
  __syncthreads();
  if (tid == 0) {
    float s = 0.f;
#pragma unroll
    for (int j = 0; j < 8; ++j) s = fmaf(wrl[j], r2[j], s);
    scal[0] = s;
    r_o[0] = s;
    scal[1] = s / diag;
  }
  __syncthreads();
  if (tid < 8) {
    int x = tid & 1, y = (tid >> 1) & 1, z = tid >> 2;
    float wp = scal[1];
    float az = azb_prol(&scal[1], 1, 2, z, y, x, wA);
    wa[tid] = wp - az/diag + r2[tid]/diag;
  }
  __syncthreads();
  if (tid < 64) {
    int x = tid & 3, y = (tid >> 2) & 3, z = tid >> 4;
    float wp = wa[((z>>1)*2 + (y>>1))*2 + (x>>1)];
    float az = azb_prol(wa, 2, 4, z, y, x, wA);
    wb[tid] = wp - az/diag + r4[tid]/diag;
  }
  __syncthreads();
  {
    int j = tid;
    int x = j & 7, y = (j >> 3) & 7, z = j >> 6;
    float wp = wb[((z>>1)*4 + (y>>1))*4 + (x>>1)];
    float az = azb_prol(wb, 4, 8, z, y, x, wA);
    wa[j] = wp - az/diag + r8[j]/diag;
  }
  __syncthreads();
  for (int j = tid; j < 4096; j += 512) {
    int x = j & 15, y = (j >> 4) & 15, z = j >> 8;
    float wp = wa[((z>>1)*8 + (y>>1))*8 + (x>>1)];
    float az = azb_prol(wa, 8, 16, z, y, x, wA);
    w16[j] = wp - az/diag + r16[j]/diag;
  }
}

__global__ void __launch_bounds__(256) k_coarse_step(
    float* __restrict__ wout, const float* __restrict__ wh,
    const float* __restrict__ rl, const float* __restrict__ wA, int s) {
  int i = blockIdx.x*256 + threadIdx.x;
  int n3 = s*s*s;
  if (i >= n3) return;
  int x = i % s; int t = i / s; int y = t % s; int z = t / s;
  int hs = s >> 1;
  float diag = wA[13];
  float wp = wh[((z>>1)*hs + (y>>1))*hs + (x>>1)];
  float az = azb_prol(wh, hs, s, z, y, x, wA);
  wout[i] = wp - az/diag + rl[i]/diag;
}

__global__ void __launch_bounds__(256) k_pupd4(
    float* __restrict__ pdst, float* __restrict__ wmgo,
    const float* __restrict__ psrc, const float* __restrict__ rfine,
    const float* __restrict__ w64, const float* __restrict__ wA, int writeWmg) {
  int i4 = blockIdx.x*256 + threadIdx.x;
  if (i4 >= NF/4) return;
  int i = i4*4;
  int x = i & (NN-1); int t = i >> 7; int y = t & (NN-1); int z = t >> 7;
  float rdiag = 1.0f / wA[13];
  float2 w2 = *(const float2*)(w64 + ((size_t)(z>>1)*64 + (y>>1))*64 + (x>>1));
  float4 ps = ((const float4*)psrc)[i4];
  float4 rf = ((const float4*)rfine)[i4];
  float4 o = make_float4(ps.x - w2.x - rf.x*rdiag,
                         ps.y - w2.x - rf.y*rdiag,
                         ps.z - w2.y - rf.z*rdiag,
                         ps.w - w2.y - rf.w*rdiag);
  ((float4*)pdst)[i4] = o;
  if (writeWmg) ((float4*)wmgo)[i4] = make_float4(w2.x, w2.x, w2.y, w2.y);
}

// Final projection (x-quad, plane-major grid).
__global__ void __launch_bounds__(256) k_proj3(
    float* __restrict__ u, float* __restrict__ v, float* __restrict__ w,
    const float* __restrict__ pf, const float* __restrict__ sg,
    const float* __restrict__ wx, const float* __restrict__ wy,
    const float* __restrict__ wz, const float* __restrict__ dtp) {
  int x0 = threadIdx.x * 4;
  int y  = blockIdx.x * 8 + threadIdx.y;
  int z  = blockIdx.y;
  bool lo = (x0 == 0), hi = (x0 == NN-4);
  int rb[9]; bool rn[9];
  prep9(z, y, rb, rn);
  float aP[3][4] = {};
  sten_p3(pf, rb, lo, hi, x0, wx, wy, wz, aP);
  float dt = dtp[0];
  int i4 = ((z*NN + y)*NN + x0) >> 2;
  float4 u4 = ((const float4*)u)[i4];
  float4 v4 = ((const float4*)v)[i4];
  float4 w4 = ((const float4*)w)[i4];
  float4 sg4 = ((const float4*)sg)[i4];
  float ua[4] = {u4.x, u4.y, u4.z, u4.w};
  float va[4] = {v4.x, v4.y, v4.z, v4.w};
  float wa[4] = {w4.x, w4.y, w4.z, w4.w};
  float sa[4] = {sg4.x, sg4.y, sg4.z, sg4.w};
  float ou[4], ov[4], ow[4];
#pragma unroll
  for (int k = 0; k < 4; ++k) {
    float d = 1.0f + dt*sa[k];
    ou[k] = (ua[k] - aP[0][k]*dt)/d;
    ov[k] = (va[k] - aP[1][k]*dt)/d;
    ow[k] = (wa[k] - aP[2][k]*dt)/d;
  }
  ((float4*)u)[i4] = make_float4(ou[0], ou[1], ou[2], ou[3]);
  ((float4*)v)[i4] = make_float4(ov[0], ov[1], ov[2], ov[3]);
  ((float4*)w)[i4] = make_float4(ow[0], ow[1], ow[2], ow[3]);
}

// ---------- launch ----------

extern "C" void kernel_launch(void* const* d_in, const int* in_sizes, int n_in,
                              void* d_out, int out_size, void* d_ws, size_t ws_size,
                              hipStream_t stream) {
  const float* values_u = (const float*)d_in[0];
  const float* values_v = (const float*)d_in[1];
  const float* values_w = (const float*)d_in[2];
  const float* values_p = (const float*)d_in[3];
  const float* sigma    = (const float*)d_in[4];
  const float* wx       = (const float*)d_in[5];
  const float* wy       = (const float*)d_in[6];
  const float* wz       = (const float*)d_in[7];
  const float* wd       = (const float*)d_in[8];
  const float* wA       = (const float*)d_in[9];
  const float* wr       = (const float*)d_in[10];
  const float* dtp      = (const float*)d_in[11];

  float* out   = (float*)d_out;
  float* u_o   = out;
  float* v_o   = out + (size_t)NF;
  float* w_o   = out + (size_t)2*NF;
  float* p_o   = out + (size_t)3*NF;
  float* wmg_o = out + (size_t)4*NF;
  float* r_o   = out + (size_t)5*NF;

  float* ws    = (float*)d_ws;
  float* f0    = ws;                     // b_u
  float* f1    = f0 + (size_t)NF;        // b_v
  float* f2    = f1 + (size_t)NF;        // b_w
  float* bws   = f2 + (size_t)NF;        // b
  float* rfine = bws + (size_t)NF;       // A(pp)-b
  float* pbuf  = rfine + (size_t)NF;     // p after iter 0
  float* rc1   = pbuf + (size_t)NF;      // 64^3
  float* rc2   = rc1 + 262144;           // 32^3
  float* w16   = rc2 + 32768;            // 16^3
  float* w32   = w16 + 4096;             // 32^3
  float* w64   = w32 + 32768;            // 64^3

  const int TB = 256;
  dim3 blkS(32, 8, 1);
  dim3 grdS(16, 128, 1);   // yband fastest, z slowest (plane-major)

  // solid
  k_solid3<<<NF/4/TB, TB, 0, stream>>>(u_o, v_o, w_o, values_u, values_v, values_w, sigma, dtp);

  // predictor (per component): dst=f*, stencil=current vel, qb aliases center
  k_momc<0, true><<<grdS, blkS, 0, stream>>>(f0, u_o, values_p, v_o, w_o, u_o, sigma,
                                             wx, wy, wz, wd, wx, dtp, 0.5f);
  k_momc<1, true><<<grdS, blkS, 0, stream>>>(f1, v_o, values_p, u_o, w_o, v_o, sigma,
                                             wx, wy, wz, wd, wy, dtp, 0.5f);
  k_momc<2, true><<<grdS, blkS, 0, stream>>>(f2, w_o, values_p, u_o, v_o, w_o, sigma,
                                             wx, wy, wz, wd, wz, dtp, 0.5f);
  // corrector: stencil=f*, qb=old vel, dst in-place
  k_momc<0, false><<<grdS, blkS, 0, stream>>>(u_o, f0, values_p, f1, f2, u_o, sigma,
                                              wx, wy, wz, wd, wx, dtp, 1.0f);
  k_momc<1, false><<<grdS, blkS, 0, stream>>>(v_o, f1, values_p, f0, f2, v_o, sigma,
                                              wx, wy, wz, wd, wy, dtp, 1.0f);
  k_momc<2, false><<<grdS, blkS, 0, stream>>>(w_o, f2, values_p, f0, f1, w_o, sigma,
                                              wx, wy, wz, wd, wz, dtp, 1.0f);

  // it 0: fused b + residual + first restriction
  k_bdiv_resres<<<1024, TB, 0, stream>>>(bws, rfine, rc1, u_o, v_o, w_o, values_p,
                                         wx, wy, wz, wA, wr, dtp);
  k_restrict<<<128, TB, 0, stream>>>(rc2, rc1, wr, 32);
  k_mg_small<<<1, 512, 0, stream>>>(w16, r_o, rc2, wA, wr);
  k_coarse_step<<<128, TB, 0, stream>>>(w32, w16, rc2, wA, 32);
  k_coarse_step<<<1024, TB, 0, stream>>>(w64, w32, rc1, wA, 64);
  k_pupd4<<<NF/4/TB, TB, 0, stream>>>(pbuf, wmg_o, values_p, rfine, w64, wA, 0);

  // it 1
  k_resres1<<<1024, TB, 0, stream>>>(rfine, rc1, pbuf, bws, wA, wr);
  k_restrict<<<128, TB, 0, stream>>>(rc2, rc1, wr, 32);
  k_mg_small<<<1, 512, 0, stream>>>(w16, r_o, rc2, wA, wr);
  k_coarse_step<<<128, TB, 0, stream>>>(w32, w16, rc2, wA, 32);
  k_coarse_step<<<1024, TB, 0, stream>>>(w64, w32, rc1, wA, 64);
  k_pupd4<<<NF/4/TB, TB, 0, stream>>>(p_o, wmg_o, pbuf, rfine, w64, wA, 1);

  // final projection
  k_proj3<<<grdS, blkS, 0, stream>>>(u_o, v_o, w_o, p_o, sigma, wx, wy, wz, dtp);
}

// Round 7
// 226.261 us; speedup vs baseline: 1.3150x; 1.3150x over previous
//
#include <hip/hip_runtime.h>

// AI4Urban fused CFD timestep on 128^3 f32 grid.
// Round 7: sweep-count reduction. k_prep does solid + ALL FOUR p-field convs
// (wx,wy,wz,wA) in one sweep, folding -grad(p)*dt into the momentum base term
// (gq_*) and precomputing ap0=A(pp). Momentum kernels: 3 sweeps each (was 4).
// bdiv_resres: 3 sweeps (was 4). Plane-major grid throughout (r5 locality).

#define NN 128
#define NF (NN*NN*NN)   // 2097152

// ---------- row prep ----------

__device__ __forceinline__ void prep9(int z, int y, int rb[9], bool rn[9]) {
  int zi[3] = {z > 0 ? z-1 : 0, z, z < NN-1 ? z+1 : NN-1};
  int yi[3] = {y > 0 ? y-1 : 0, y, y < NN-1 ? y+1 : NN-1};
  bool zo[3] = {z == 0, false, z == NN-1};
  bool yo[3] = {y == 0, false, y == NN-1};
#pragma unroll
  for (int a = 0; a < 3; ++a)
#pragma unroll
    for (int b = 0; b < 3; ++b) {
      rb[a*3+b] = (zi[a]*NN + yi[b])*NN;
      rn[a*3+b] = zo[a] | yo[b];
    }
}

// 4-set x-quad stencil over one field; optional center return.
template<bool NEG>
__device__ __forceinline__ void sten4(
    const float* __restrict__ f, const int rb[9], const bool rn[9],
    bool lo, bool hi, int x0,
    const float* __restrict__ w0p, const float* __restrict__ w1p,
    const float* __restrict__ w2p, const float* __restrict__ w3p,
    float acc[4][4], float4* center) {
  const float* const Ws[4] = {w0p, w1p, w2p, w3p};
#pragma unroll
  for (int r = 0; r < 9; ++r) {
    int base = rb[r] + x0;
    float4 c = *(const float4*)(f + base);
    float m1 = f[base - (lo ? 0 : 1)];
    float p4 = f[base + (hi ? 3 : 4)];
    if (NEG) {
      float sr = rn[r] ? -1.f : 1.f;
      m1 *= (rn[r] | lo) ? -1.f : 1.f;
      p4 *= (rn[r] | hi) ? -1.f : 1.f;
      c.x *= sr; c.y *= sr; c.z *= sr; c.w *= sr;
    }
    if (r == 4 && center) *center = c;
    float t[6] = {m1, c.x, c.y, c.z, c.w, p4};
#pragma unroll
    for (int s = 0; s < 4; ++s) {
      const float* W = Ws[s];
      float a0 = W[r*3+0], a1 = W[r*3+1], a2 = W[r*3+2];
#pragma unroll
      for (int k = 0; k < 4; ++k)
        acc[s][k] = fmaf(a0, t[k], fmaf(a1, t[k+1], fmaf(a2, t[k+2], acc[s][k])));
    }
  }
}

// 3-set stencil (projection).
__device__ __forceinline__ void sten_p3(
    const float* __restrict__ f, const int rb[9],
    bool lo, bool hi, int x0,
    const float* __restrict__ w0p, const float* __restrict__ w1p,
    const float* __restrict__ w2p, float acc[3][4]) {
  const float* const Ws[3] = {w0p, w1p, w2p};
#pragma unroll
  for (int r = 0; r < 9; ++r) {
    int base = rb[r] + x0;
    float4 c = *(const float4*)(f + base);
    float m1 = f[base - (lo ? 0 : 1)];
    float p4 = f[base + (hi ? 3 : 4)];
    float t[6] = {m1, c.x, c.y, c.z, c.w, p4};
#pragma unroll
    for (int s = 0; s < 3; ++s) {
      const float* W = Ws[s];
      float a0 = W[r*3+0], a1 = W[r*3+1], a2 = W[r*3+2];
#pragma unroll
      for (int k = 0; k < 4; ++k)
        acc[s][k] = fmaf(a0, t[k], fmaf(a1, t[k+1], fmaf(a2, t[k+2], acc[s][k])));
    }
  }
}

// ---------- kernels ----------

// prep: one sweep of values_p with 4 weight sets {wx,wy,wz,wA} + solid.
// Writes: u_o=vu/d, v_o, w_o; gq_* = (v*/d) - grad_p*dt; ap0 = A(pp).
__global__ void __launch_bounds__(256) k_prep(
    float* __restrict__ uo, float* __restrict__ vo, float* __restrict__ wo,
    float* __restrict__ gqu, float* __restrict__ gqv, float* __restrict__ gqw,
    float* __restrict__ ap0,
    const float* __restrict__ vu, const float* __restrict__ vv, const float* __restrict__ vw,
    const float* __restrict__ pf, const float* __restrict__ sg,
    const float* __restrict__ wx, const float* __restrict__ wy,
    const float* __restrict__ wz, const float* __restrict__ wA,
    const float* __restrict__ dtp) {
  int x0 = threadIdx.x * 4;
  int y  = blockIdx.x * 8 + threadIdx.y;
  int z  = blockIdx.y;
  bool lo = (x0 == 0), hi = (x0 == NN-4);
  int rb[9]; bool rn[9];
  prep9(z, y, rb, rn);
  float dt = dtp[0];
  int i4 = ((z*NN + y)*NN + x0) >> 2;

  float4 u4 = ((const float4*)vu)[i4];
  float4 v4 = ((const float4*)vv)[i4];
  float4 w4 = ((const float4*)vw)[i4];
  float4 s4 = ((const float4*)sg)[i4];

  float aP[4][4] = {};
  sten4<false>(pf, rb, rn, lo, hi, x0, wx, wy, wz, wA, aP, (float4*)nullptr);

  float uv[4] = {u4.x, u4.y, u4.z, u4.w};
  float vv_[4] = {v4.x, v4.y, v4.z, v4.w};
  float wv[4] = {w4.x, w4.y, w4.z, w4.w};
  float sv[4] = {s4.x, s4.y, s4.z, s4.w};
  float ou[4], ov[4], ow[4], gu[4], gv[4], gw[4];
#pragma unroll
  for (int k = 0; k < 4; ++k) {
    float rd = 1.0f / (1.0f + dt*sv[k]);
    ou[k] = uv[k]*rd; ov[k] = vv_[k]*rd; ow[k] = wv[k]*rd;
    gu[k] = ou[k] - aP[0][k]*dt;
    gv[k] = ov[k] - aP[1][k]*dt;
    gw[k] = ow[k] - aP[2][k]*dt;
  }
  ((float4*)uo)[i4]  = make_float4(ou[0], ou[1], ou[2], ou[3]);
  ((float4*)vo)[i4]  = make_float4(ov[0], ov[1], ov[2], ov[3]);
  ((float4*)wo)[i4]  = make_float4(ow[0], ow[1], ow[2], ow[3]);
  ((float4*)gqu)[i4] = make_float4(gu[0], gu[1], gu[2], gu[3]);
  ((float4*)gqv)[i4] = make_float4(gv[0], gv[1], gv[2], gv[3]);
  ((float4*)gqw)[i4] = make_float4(gw[0], gw[1], gw[2], gw[3]);
  ((float4*)ap0)[i4] = make_float4(aP[3][0], aP[3][1], aP[3][2], aP[3][3]);
}

// Momentum (3 sweeps): dst_c = (gq_c + scale*dt*(0.001*k_c - adv_c)) / d.
__global__ void __launch_bounds__(256) k_mom3(
    float* __restrict__ du, float* __restrict__ dv, float* __restrict__ dw,
    const float* __restrict__ su, const float* __restrict__ sv, const float* __restrict__ sw,
    const float* __restrict__ gqu, const float* __restrict__ gqv, const float* __restrict__ gqw,
    const float* __restrict__ sg,
    const float* __restrict__ wx, const float* __restrict__ wy,
    const float* __restrict__ wz, const float* __restrict__ wd,
    const float* __restrict__ dtp, float scale) {
  int x0 = threadIdx.x * 4;
  int y  = blockIdx.x * 8 + threadIdx.y;
  int z  = blockIdx.y;
  bool lo = (x0 == 0), hi = (x0 == NN-4);
  int rb[9]; bool rn[9];
  prep9(z, y, rb, rn);
  float dt = dtp[0];
  int i4 = ((z*NN + y)*NN + x0) >> 2;

  float4 gu4 = ((const float4*)gqu)[i4];
  float4 gv4 = ((const float4*)gqv)[i4];
  float4 gw4 = ((const float4*)gqw)[i4];
  float4 sg4 = ((const float4*)sg)[i4];

  float aU[4][4] = {}, aV[4][4] = {}, aW[4][4] = {};
  float4 uc, vc, wc;
  sten4<true >(su, rb, rn, lo, hi, x0, wx, wy, wz, wd, aU, &uc);
  sten4<false>(sv, rb, rn, lo, hi, x0, wx, wy, wz, wd, aV, &vc);
  sten4<false>(sw, rb, rn, lo, hi, x0, wx, wy, wz, wd, aW, &wc);

  float sw27 = 0.f;
#pragma unroll
  for (int j = 0; j < 27; ++j) sw27 += wd[j];

  float ucv[4] = {uc.x, uc.y, uc.z, uc.w};
  float vcv[4] = {vc.x, vc.y, vc.z, vc.w};
  float wcv[4] = {wc.x, wc.y, wc.z, wc.w};
  float guv[4] = {gu4.x, gu4.y, gu4.z, gu4.w};
  float gvv[4] = {gv4.x, gv4.y, gv4.z, gv4.w};
  float gwv[4] = {gw4.x, gw4.y, gw4.z, gw4.w};
  float sgv[4] = {sg4.x, sg4.y, sg4.z, sg4.w};
  float ou[4], ov[4], ow[4];
#pragma unroll
  for (int k = 0; k < 4; ++k) {
    float ku = aU[3][k] - 0.5f*sw27*ucv[k];
    float kv = aV[3][k] - 0.5f*sw27*vcv[k];
    float kw = aW[3][k] - 0.5f*sw27*wcv[k];
    float ru = guv[k] + scale*dt*(0.001f*ku - ucv[k]*aU[0][k] - vcv[k]*aU[1][k] - wcv[k]*aU[2][k]);
    float rv = gvv[k] + scale*dt*(0.001f*kv - ucv[k]*aV[0][k] - vcv[k]*aV[1][k] - wcv[k]*aV[2][k]);
    float rw = gwv[k] + scale*dt*(0.001f*kw - ucv[k]*aW[0][k] - vcv[k]*aW[1][k] - wcv[k]*aW[2][k]);
    float rd = 1.0f / (1.0f + dt*sgv[k]);
    ou[k] = ru*rd; ov[k] = rv*rd; ow[k] = rw*rd;
  }
  ((float4*)du)[i4] = make_float4(ou[0], ou[1], ou[2], ou[3]);
  ((float4*)dv)[i4] = make_float4(ov[0], ov[1], ov[2], ov[3]);
  ((float4*)dw)[i4] = make_float4(ow[0], ow[1], ow[2], ow[3]);
}

// ---------- coarse-cell kernels (2x2x2 fine ownership, plane-streamed) ----------

__device__ __forceinline__ void row4(const float* __restrict__ f, int base,
                                     bool lo, bool hi, float t[4]) {
  float2 c = *(const float2*)(f + base);
  t[0] = f[base - (lo ? 0 : 1)];
  t[1] = c.x; t[2] = c.y;
  t[3] = f[base + (hi ? 1 : 2)];
}

__device__ __forceinline__ void prep16(int Z, int Y, int rb[16], bool rn[16]) {
  int z0 = 2*Z, y0 = 2*Y;
  int zi[4] = {z0 > 0 ? z0-1 : 0, z0, z0+1, z0+2 < NN ? z0+2 : NN-1};
  int yi[4] = {y0 > 0 ? y0-1 : 0, y0, y0+1, y0+2 < NN ? y0+2 : NN-1};
  bool zo[4] = {Z == 0, false, false, Z == 63};
  bool yo[4] = {Y == 0, false, false, Y == 63};
#pragma unroll
  for (int a = 0; a < 4; ++a)
#pragma unroll
    for (int b = 0; b < 4; ++b) {
      rb[a*4+b] = (zi[a]*NN + yi[b])*NN;
      rn[a*4+b] = zo[a] | yo[b];
    }
}

template<bool NEG>
__device__ __forceinline__ void cc_acc(
    const float* __restrict__ f, const float* __restrict__ W,
    const int rb[16], const bool rn[16], bool lo, bool hi, int x0,
    float out8[8]) {
#pragma unroll
  for (int zp = 0; zp < 4; ++zp) {
    float t[4][4];
#pragma unroll
    for (int yp = 0; yp < 4; ++yp) {
      row4(f, rb[zp*4+yp] + x0, lo, hi, t[yp]);
      if (NEG) {
        bool rno = rn[zp*4+yp];
        float sr = rno ? -1.f : 1.f;
        t[yp][1] *= sr; t[yp][2] *= sr;
        t[yp][0] *= (rno | lo) ? -1.f : 1.f;
        t[yp][3] *= (rno | hi) ? -1.f : 1.f;
      }
    }
#pragma unroll
    for (int dz = 0; dz < 2; ++dz) {
      int a = zp - dz;
      if (a < 0 || a > 2) continue;
#pragma unroll
      for (int oy = 0; oy < 2; ++oy)
#pragma unroll
        for (int b = 0; b < 3; ++b) {
          const float* tr = t[oy + b];
          float w0 = W[(a*3+b)*3+0], w1 = W[(a*3+b)*3+1], w2 = W[(a*3+b)*3+2];
#pragma unroll
          for (int dx = 0; dx < 2; ++dx)
            out8[(dz*2+oy)*2+dx] =
              fmaf(w0, tr[dx], fmaf(w1, tr[dx+1], fmaf(w2, tr[dx+2], out8[(dz*2+oy)*2+dx])));
        }
    }
  }
}

// it0: b = -(div)/dt (3 sweeps), rfine = ap0 - b (ap0 pointwise), rc1 = restrict.
__global__ void __launch_bounds__(256) k_bdivres0(
    float* __restrict__ bb, float* __restrict__ rfine, float* __restrict__ rc1,
    const float* __restrict__ su, const float* __restrict__ sv, const float* __restrict__ sw,
    const float* __restrict__ ap0,
    const float* __restrict__ wx, const float* __restrict__ wy, const float* __restrict__ wz,
    const float* __restrict__ wr, const float* __restrict__ dtp) {
  int i = blockIdx.x*256 + threadIdx.x;
  if (i >= 64*64*64) return;
  int X = i & 63, Y = (i >> 6) & 63, Z = i >> 12;
  bool lo = (X == 0), hi = (X == 63);
  int x0 = 2*X;
  int rb[16]; bool rn[16];
  prep16(Z, Y, rb, rn);
  float rdt = 1.0f / dtp[0];

  float s8[8] = {};
  cc_acc<true >(su, wx, rb, rn, lo, hi, x0, s8);
  cc_acc<false>(sv, wy, rb, rn, lo, hi, x0, s8);
  cc_acc<false>(sw, wz, rb, rn, lo, hi, x0, s8);

  float rsum = 0.f;
#pragma unroll
  for (int dz = 0; dz < 2; ++dz)
#pragma unroll
    for (int oy = 0; oy < 2; ++oy) {
      int fi = ((2*Z+dz)*NN + (2*Y+oy))*NN + x0;
      float2 a2 = *(const float2*)(ap0 + fi);
      float av[2] = {a2.x, a2.y};
#pragma unroll
      for (int dx = 0; dx < 2; ++dx) {
        int f = (dz*2+oy)*2+dx;
        float bcell = -s8[f] * rdt;
        float rcell = av[dx] - bcell;
        bb[fi+dx] = bcell;
        rfine[fi+dx] = rcell;
        rsum = fmaf(wr[f], rcell, rsum);
      }
    }
  rc1[i] = rsum;
}

// it>=1 residual: rfine = A(pst) - b, rc1 = restrict(rfine).
__global__ void __launch_bounds__(256) k_resres1(
    float* __restrict__ rfine, float* __restrict__ rc1,
    const float* __restrict__ pf, const float* __restrict__ bb,
    const float* __restrict__ wA, const float* __restrict__ wr) {
  int i = blockIdx.x*256 + threadIdx.x;
  if (i >= 64*64*64) return;
  int X = i & 63, Y = (i >> 6) & 63, Z = i >> 12;
  bool lo = (X == 0), hi = (X == 63);
  int x0 = 2*X;
  int rb[16]; bool rn[16];
  prep16(Z, Y, rb, rn);
  float a8[8] = {};
  cc_acc<false>(pf, wA, rb, rn, lo, hi, x0, a8);
  float rsum = 0.f;
#pragma unroll
  for (int f = 0; f < 8; ++f) {
    int dz = f >> 2, dy = (f >> 1) & 1, dx = f & 1;
    int idx = ((2*Z+dz)*NN + (2*Y+dy))*NN + x0 + dx;
    float rcell = a8[f] - bb[idx];
    rfine[idx] = rcell;
    rsum = fmaf(wr[(dz*2+dy)*2+dx], rcell, rsum);
  }
  rc1[i] = rsum;
}

__global__ void __launch_bounds__(256) k_restrict(
    float* __restrict__ dst, const float* __restrict__ src,
    const float* __restrict__ wr, int no) {
  int i = blockIdx.x*256 + threadIdx.x;
  int n3 = no*no*no;
  if (i >= n3) return;
  int x = i % no; int t = i / no; int y = t % no; int z = t / no;
  int ni = 2*no;
  float s = 0.f;
#pragma unroll
  for (int a = 0; a < 2; ++a)
#pragma unroll
    for (int b = 0; b < 2; ++b)
#pragma unroll
      for (int c = 0; c < 2; ++c)
        s = fmaf(wr[(a*2+b)*2+c], src[((2*z+a)*ni + (2*y+b))*ni + (2*x+c)], s);
  dst[i] = s;
}

__device__ __forceinline__ float azb_prol(const float* __restrict__ wh, int hs, int s,
    int z, int y, int x, const float* __restrict__ wA) {
  float acc = 0.f;
#pragma unroll
  for (int a = 0; a < 3; ++a) { int zz = z + a - 1; if ((unsigned)zz >= (unsigned)s) continue;
#pragma unroll
    for (int b = 0; b < 3; ++b) { int yy = y + b - 1; if ((unsigned)yy >= (unsigned)s) continue;
#pragma unroll
      for (int c = 0; c < 3; ++c) { int xx = x + c - 1; if ((unsigned)xx >= (unsigned)s) continue;
        acc = fmaf(wA[(a*3+b)*3+c], wh[((zz>>1)*hs + (yy>>1))*hs + (xx>>1)], acc);
      } } }
  return acc;
}

__global__ void __launch_bounds__(512) k_mg_small(
    float* __restrict__ w16, float* __restrict__ r_o,
    const float* __restrict__ rc2,
    const float* __restrict__ wA, const float* __restrict__ wr) {
  __shared__ float r16[4096];
  __shared__ float r8[512];
  __shared__ float r4[64];
  __shared__ float r2[8];
  __shared__ float wa[512];
  __shared__ float wb[64];
  __shared__ float scal[2];
  int tid = threadIdx.x;
  float diag = wA[13];
  float wrl[8];
#pragma unroll
  for (int j = 0; j < 8; ++j) wrl[j] = wr[j];

  for (int j = tid; j < 4096; j += 512) {
    int x = j & 15, y = (j >> 4) & 15, z = j >> 8;
    float s = 0.f;
#pragma unroll
    for (int a = 0; a < 2; ++a)
#pragma unroll
      for (int b = 0; b < 2; ++b)
#pragma unroll
        for (int c = 0; c < 2; ++c)
          s = fmaf(wrl[(a*2+b)*2+c], rc2[((2*z+a)*32 + (2*y+b))*32 + (2*x+c)], s);
    r16[j] = s;
  }
  __syncthreads();
  {
    int j = tid;
    int x = j & 7, y = (j >> 3) & 7, z = j >> 6;
    float s = 0.f;
#pragma unroll
    for (int a = 0; a < 2; ++a)
#pragma unroll
      for (int b = 0; b < 2; ++b)
#pragma unroll
        for (int c = 0; c < 2; ++c)
          s = fmaf(wrl[(a*2+b)*2+c], r16[((2*z+a)*16 + (2*y+b))*16 + (2*x+c)], s);
    r8[j] = s;
  }
  __syncthreads();
  if (tid < 64) {
    int x = tid & 3, y = (tid >> 2) & 3, z = tid >> 4;
    float s = 0.f;
#pragma unroll
    for (int a = 0; a < 2; ++a)
#pragma unroll
      for (int b = 0; b < 2; ++b)
#pragma unroll
        for (int c = 0; c < 2; ++c)
          s = fmaf(wrl[(a*2+b)*2+c], r8[((2*z+a)*8 + (2*y+b))*8 + (2*x+c)], s);
    r4[tid] = s;
  }
  __syncthreads();
  if (tid < 8) {
    int x = tid & 1, y = (tid >> 1) & 1, z = tid >> 2;
    float s = 0.f;
#pragma unroll
    for (int a = 0; a < 2; ++a)
#pragma unroll
      for (int b = 0; b < 2; ++b)
#pragma unroll
        for (int c = 0; c < 2; ++c)
          s = fmaf(wrl[(a*2+b)*2+c], r4[((2*z+a)*4 + (2*y+b))*4 + (2*x+c)], s);
    r2[tid] = s;
  }
  __syncthreads();
  if (tid == 0) {
    float s = 0.f;
#pragma unroll
    for (int j = 0; j < 8; ++j) s = fmaf(wrl[j], r2[j], s);
    scal[0] = s;
    r_o[0] = s;
    scal[1] = s / diag;
  }
  __syncthreads();
  if (tid < 8) {
    int x = tid & 1, y = (tid >> 1) & 1, z = tid >> 2;
    float wp = scal[1];
    float az = azb_prol(&scal[1], 1, 2, z, y, x, wA);
    wa[tid] = wp - az/diag + r2[tid]/diag;
  }
  __syncthreads();
  if (tid < 64) {
    int x = tid & 3, y = (tid >> 2) & 3, z = tid >> 4;
    float wp = wa[((z>>1)*2 + (y>>1))*2 + (x>>1)];
    float az = azb_prol(wa, 2, 4, z, y, x, wA);
    wb[tid] = wp - az/diag + r4[tid]/diag;
  }
  __syncthreads();
  {
    int j = tid;
    int x = j & 7, y = (j >> 3) & 7, z = j >> 6;
    float wp = wb[((z>>1)*4 + (y>>1))*4 + (x>>1)];
    float az = azb_prol(wb, 4, 8, z, y, x, wA);
    wa[j] = wp - az/diag + r8[j]/diag;
  }
  __syncthreads();
  for (int j = tid; j < 4096; j += 512) {
    int x = j & 15, y = (j >> 4) & 15, z = j >> 8;
    float wp = wa[((z>>1)*8 + (y>>1))*8 + (x>>1)];
    float az = azb_prol(wa, 8, 16, z, y, x, wA);
    w16[j] = wp - az/diag + r16[j]/diag;
  }
}

__global__ void __launch_bounds__(256) k_coarse_step(
    float* __restrict__ wout, const float* __restrict__ wh,
    const float* __restrict__ rl, const float* __restrict__ wA, int s) {
  int i = blockIdx.x*256 + threadIdx.x;
  int n3 = s*s*s;
  if (i >= n3) return;
  int x = i % s; int t = i / s; int y = t % s; int z = t / s;
  int hs = s >> 1;
  float diag = wA[13];
  float wp = wh[((z>>1)*hs + (y>>1))*hs + (x>>1)];
  float az = azb_prol(wh, hs, s, z, y, x, wA);
  wout[i] = wp - az/diag + rl[i]/diag;
}

__global__ void __launch_bounds__(256) k_pupd4(
    float* __restrict__ pdst, float* __restrict__ wmgo,
    const float* __restrict__ psrc, const float* __restrict__ rfine,
    const float* __restrict__ w64, const float* __restrict__ wA, int writeWmg) {
  int i4 = blockIdx.x*256 + threadIdx.x;
  if (i4 >= NF/4) return;
  int i = i4*4;
  int x = i & (NN-1); int t = i >> 7; int y = t & (NN-1); int z = t >> 7;
  float rdiag = 1.0f / wA[13];
  float2 w2 = *(const float2*)(w64 + ((size_t)(z>>1)*64 + (y>>1))*64 + (x>>1));
  float4 ps = ((const float4*)psrc)[i4];
  float4 rf = ((const float4*)rfine)[i4];
  float4 o = make_float4(ps.x - w2.x - rf.x*rdiag,
                         ps.y - w2.x - rf.y*rdiag,
                         ps.z - w2.y - rf.z*rdiag,
                         ps.w - w2.y - rf.w*rdiag);
  ((float4*)pdst)[i4] = o;
  if (writeWmg) ((float4*)wmgo)[i4] = make_float4(w2.x, w2.x, w2.y, w2.y);
}

// Final projection (x-quad, plane-major grid).
__global__ void __launch_bounds__(256) k_proj3(
    float* __restrict__ u, float* __restrict__ v, float* __restrict__ w,
    const float* __restrict__ pf, const float* __restrict__ sg,
    const float* __restrict__ wx, const float* __restrict__ wy,
    const float* __restrict__ wz, const float* __restrict__ dtp) {
  int x0 = threadIdx.x * 4;
  int y  = blockIdx.x * 8 + threadIdx.y;
  int z  = blockIdx.y;
  bool lo = (x0 == 0), hi = (x0 == NN-4);
  int rb[9]; bool rn[9];
  prep9(z, y, rb, rn);
  float aP[3][4] = {};
  sten_p3(pf, rb, lo, hi, x0, wx, wy, wz, aP);
  float dt = dtp[0];
  int i4 = ((z*NN + y)*NN + x0) >> 2;
  float4 u4 = ((const float4*)u)[i4];
  float4 v4 = ((const float4*)v)[i4];
  float4 w4 = ((const float4*)w)[i4];
  float4 sg4 = ((const float4*)sg)[i4];
  float ua[4] = {u4.x, u4.y, u4.z, u4.w};
  float va[4] = {v4.x, v4.y, v4.z, v4.w};
  float wa[4] = {w4.x, w4.y, w4.z, w4.w};
  float sa[4] = {sg4.x, sg4.y, sg4.z, sg4.w};
  float ou[4], ov[4], ow[4];
#pragma unroll
  for (int k = 0; k < 4; ++k) {
    float rd = 1.0f / (1.0f + dt*sa[k]);
    ou[k] = (ua[k] - aP[0][k]*dt)*rd;
    ov[k] = (va[k] - aP[1][k]*dt)*rd;
    ow[k] = (wa[k] - aP[2][k]*dt)*rd;
  }
  ((float4*)u)[i4] = make_float4(ou[0], ou[1], ou[2], ou[3]);
  ((float4*)v)[i4] = make_float4(ov[0], ov[1], ov[2], ov[3]);
  ((float4*)w)[i4] = make_float4(ow[0], ow[1], ow[2], ow[3]);
}

// ---------- launch ----------

extern "C" void kernel_launch(void* const* d_in, const int* in_sizes, int n_in,
                              void* d_out, int out_size, void* d_ws, size_t ws_size,
                              hipStream_t stream) {
  const float* values_u = (const float*)d_in[0];
  const float* values_v = (const float*)d_in[1];
  const float* values_w = (const float*)d_in[2];
  const float* values_p = (const float*)d_in[3];
  const float* sigma    = (const float*)d_in[4];
  const float* wx       = (const float*)d_in[5];
  const float* wy       = (const float*)d_in[6];
  const float* wz       = (const float*)d_in[7];
  const float* wd       = (const float*)d_in[8];
  const float* wA       = (const float*)d_in[9];
  const float* wr       = (const float*)d_in[10];
  const float* dtp      = (const float*)d_in[11];

  float* out   = (float*)d_out;
  float* u_o   = out;
  float* v_o   = out + (size_t)NF;
  float* w_o   = out + (size_t)2*NF;
  float* p_o   = out + (size_t)3*NF;
  float* wmg_o = out + (size_t)4*NF;
  float* r_o   = out + (size_t)5*NF;

  float* ws    = (float*)d_ws;
  float* f0    = ws;                     // b_u
  float* f1    = f0 + (size_t)NF;        // b_v
  float* f2    = f1 + (size_t)NF;        // b_w
  float* bws   = f2 + (size_t)NF;        // b
  float* rfine = bws + (size_t)NF;       // A(pp)-b
  float* pbuf  = rfine + (size_t)NF;     // p after iter 0
  float* gqu   = pbuf + (size_t)NF;      // u/d - px*dt
  float* gqv   = gqu + (size_t)NF;
  float* gqw   = gqv + (size_t)NF;
  float* ap0   = gqw + (size_t)NF;       // A(pp) for it0
  float* rc1   = ap0 + (size_t)NF;       // 64^3
  float* rc2   = rc1 + 262144;           // 32^3
  float* w16   = rc2 + 32768;            // 16^3
  float* w32   = w16 + 4096;             // 32^3
  float* w64   = w32 + 32768;            // 64^3

  const int TB = 256;
  dim3 blkS(32, 8, 1);
  dim3 grdS(16, 128, 1);   // yband fastest, z slowest (plane-major)

  // prep: solid + all four p-convs in one sweep
  k_prep<<<grdS, blkS, 0, stream>>>(u_o, v_o, w_o, gqu, gqv, gqw, ap0,
                                    values_u, values_v, values_w, values_p, sigma,
                                    wx, wy, wz, wA, dtp);
  // predictor / corrector (3 sweeps each)
  k_mom3<<<grdS, blkS, 0, stream>>>(f0, f1, f2, u_o, v_o, w_o, gqu, gqv, gqw,
                                    sigma, wx, wy, wz, wd, dtp, 0.5f);
  k_mom3<<<grdS, blkS, 0, stream>>>(u_o, v_o, w_o, f0, f1, f2, gqu, gqv, gqw,
                                    sigma, wx, wy, wz, wd, dtp, 1.0f);

  // it 0: b + residual (ap0 pointwise) + first restriction
  k_bdivres0<<<1024, TB, 0, stream>>>(bws, rfine, rc1, u_o, v_o, w_o, ap0,
                                      wx, wy, wz, wr, dtp);
  k_restrict<<<128, TB, 0, stream>>>(rc2, rc1, wr, 32);
  k_mg_small<<<1, 512, 0, stream>>>(w16, r_o, rc2, wA, wr);
  k_coarse_step<<<128, TB, 0, stream>>>(w32, w16, rc2, wA, 32);
  k_coarse_step<<<1024, TB, 0, stream>>>(w64, w32, rc1, wA, 64);
  k_pupd4<<<NF/4/TB, TB, 0, stream>>>(pbuf, wmg_o, values_p, rfine, w64, wA, 0);

  // it 1
  k_resres1<<<1024, TB, 0, stream>>>(rfine, rc1, pbuf, bws, wA, wr);
  k_restrict<<<128, TB, 0, stream>>>(rc2, rc1, wr, 32);
  k_mg_small<<<1, 512, 0, stream>>>(w16, r_o, rc2, wA, wr);
  k_coarse_step<<<128, TB, 0, stream>>>(w32, w16, rc2, wA, 32);
  k_coarse_step<<<1024, TB, 0, stream>>>(w64, w32, rc1, wA, 64);
  k_pupd4<<<NF/4/TB, TB, 0, stream>>>(p_o, wmg_o, pbuf, rfine, w64, wA, 1);

  // final projection
  k_proj3<<<grdS, blkS, 0, stream>>>(u_o, v_o, w_o, p_o, sigma, wx, wy, wz, dtp);
}